// Round 9
// baseline (1998.326 us; speedup 1.0000x reference)
//
#include <hip/hip_runtime.h>

#define WAY   100
#define SHOT  5
#define NQ    15
#define DD    4096
#define N_L   500
#define N_U   1500
#define N_TOT 2000
#define LAMF  10.0f
#define EPSF  1e-6f
#define MAXIT 1000

// ---- workspace layout (float offsets) ----
#define OFF_Z      0u          // Z fp32 2000*4096. After preproc: Zb bf16 (3072000 fl) at 0,
                               //   CPp (8*409600 fl) at 3145728 (dead fp32 Z region)
#define OFF_CPP    3145728u
#define OFF_MEANL  8192000u    // 4096 col sums
#define OFF_MEANU  8196096u    // 4096
#define OFF_SL     8200192u    // 100*4096
#define OFF_MUSA   8609792u    // 112*4096
#define OFF_MUSB   9068544u    // 112*4096
#define OFF_MUSQP  9527296u    // 100*256 musq partials [w][0..3] from musup, rest zero (musinit)
#define OFF_MUSB16 9552896u    // bf16 mus 112*4096 sh = 229376 fl
#define OFF_PTH    9782272u    // bf16 P^T hi 112*1536 sh = 86016 fl
#define OFF_PTL    9868288u    // bf16 P^T lo 112*1536 sh = 86016 fl
#define OFF_KMAT   9954304u    // 150000 (+pad)
#define OFF_COLS   10104320u   // colsP lines [2][32][128] = 8192 fl; slot100=maxerr slot101=tag
#define OFF_MISC   10113920u   // [3]=Ksum(f) [5]=ctr [8+16b]=cold barrier slots (b<32)
#define OFF_ZUT    10114688u   // bf16 Zu^T hi 4096*1536 sh = 3145728 fl
#define OFF_ZUTL   13260416u   // bf16 Zu^T lo 4096*1536 sh = 3145728 fl -> ends 16406144
#define OFF_AG     16406144u   // warm-start a, 1504 fl (sentinel -1 = cold)
#define OFF_PREVG  16407680u   // warm-start prev rowsums, 1504 fl
#define OFF_BINIT  16409216u   // warm-start b, 128 fl

#define SINK_BLOCKS 32         // block-count curve: 8=2100, 16=1966 (R6 A/B); this round: 32
#define SINK_T 512
#define RPB 47                 // rows per sinkhorn block (32*47 = 1504; last block 43)
#define CPR 6                  // rows per col-pass chunk (8 chunks cover 47)
#define PTS 1536               // P^T / ZuT row stride (shorts)
#define CPS 409600u            // CP partial stride (100*4096)

typedef __attribute__((ext_vector_type(8))) short short8_t;
typedef __attribute__((ext_vector_type(4))) float f32x4;

__device__ __forceinline__ short f2bs(float f) {   // fp32 -> bf16 RNE
  unsigned u = __float_as_uint(f);
  unsigned r = (u + 0x7FFFu + ((u >> 16) & 1u)) >> 16;
  return (short)r;
}
__device__ __forceinline__ float bs2f(short s) {
  return __uint_as_float(((unsigned)(unsigned short)s) << 16);
}

// relaxed agent-scope (LLC, sc1) atomics: cross-XCD exchange without wbl2/inv fences (R1-proven)
__device__ __forceinline__ float ld_agent(const float* p) {
  return __hip_atomic_load(p, __ATOMIC_RELAXED, __HIP_MEMORY_SCOPE_AGENT);
}
__device__ __forceinline__ void st_agent(float* p, float v) {
  __hip_atomic_store(p, v, __ATOMIC_RELAXED, __HIP_MEMORY_SCOPE_AGENT);
}

// ---------------- preprocessing ----------------
__global__ __launch_bounds__(256) void k_pow_norm(const float* __restrict__ X, float* __restrict__ Z,
                                                  float* __restrict__ msums, unsigned* __restrict__ misc_u,
                                                  float* __restrict__ aG, float* __restrict__ colsP) {
  int i = blockIdx.x, tid = threadIdx.x;
  __shared__ float red[256];
  if (i < 32) msums[i * 256 + tid] = 0.f;
  if (i == 32) { misc_u[tid] = 0u; misc_u[tid + 256] = 0u; misc_u[tid + 512] = 0u; }
  if (i == 33) { for (int z = tid; z < 1504; z += 256) aG[z] = -1.f; }   // cold sentinel
  if (i == 34 && tid < 64)                                               // zero 2x32 exchange tags
    st_agent(colsP + (tid >> 5) * 4096 + (tid & 31) * 128 + 101, 0.f);
  const float* x = X + (size_t)i * DD;
  float s = 0.f;
  for (int k = tid; k < DD; k += 256) s += x[k] + 1e-6f;
  red[tid] = s; __syncthreads();
  for (int o = 128; o > 0; o >>= 1) { if (tid < o) red[tid] += red[tid + o]; __syncthreads(); }
  float inv = 1.0f / fmaxf(sqrtf(red[0]), 1e-12f);
  float* z = Z + (size_t)i * DD;
  for (int k = tid; k < DD; k += 256) z[k] = sqrtf(x[k] + 1e-6f) * inv;
}

__global__ __launch_bounds__(256) void k_colmeans(const float* __restrict__ Z, float* __restrict__ mLs,
                                                  float* __restrict__ mUs) {
  int k = blockIdx.x * 256 + threadIdx.x;
  int r0 = blockIdx.y * 80;
  float sL = 0.f, sU = 0.f;
  for (int r = r0; r < r0 + 80; ++r) {
    float v = Z[(size_t)r * DD + k];
    if (r < N_L) sL += v; else sU += v;
  }
  if (r0 < N_L) atomicAdd(&mLs[k], sL);
  if (r0 + 80 > N_L) atomicAdd(&mUs[k], sU);
}

__global__ __launch_bounds__(256) void k_center(float* __restrict__ Z, const float* __restrict__ mLs,
                                                const float* __restrict__ mUs) {
  int i = blockIdx.x, tid = threadIdx.x;
  __shared__ float red[256];
  const float* m = (i < N_L) ? mLs : mUs;
  const float scale = (i < N_L) ? (1.0f / 500.0f) : (1.0f / 1500.0f);
  float* z = Z + (size_t)i * DD;
  float s = 0.f;
  for (int k = tid; k < DD; k += 256) { float v = z[k] - m[k] * scale; s += v * v; }
  red[tid] = s; __syncthreads();
  for (int o = 128; o > 0; o >>= 1) { if (tid < o) red[tid] += red[tid + o]; __syncthreads(); }
  float inv = 1.0f / fmaxf(sqrtf(red[0]), 1e-12f);
  for (int k = tid; k < DD; k += 256) z[k] = (z[k] - m[k] * scale) * inv;
}

// musinit also one-time zeroes PT pad cols 1500..1503 (rows 0..99); sink never writes them.
__global__ __launch_bounds__(256) void k_musinit(const float* __restrict__ Z, float* __restrict__ SL,
                                                 float* __restrict__ mus, short* __restrict__ musb,
                                                 float* __restrict__ musqP, float* __restrict__ binit,
                                                 short* __restrict__ PTH, short* __restrict__ PTL) {
  int w = blockIdx.x, tid = threadIdx.x;
  __shared__ float red[256];
  if (tid == 0) binit[w] = 1.0f;
  if (tid >= 4 && tid < 8) PTH[(size_t)w * PTS + 1500 + (tid - 4)] = 0;
  if (tid >= 8 && tid < 12) PTL[(size_t)w * PTS + 1500 + (tid - 8)] = 0;
  float q = 0.f;
  for (int k = tid; k < DD; k += 256) {
    float s = 0.f;
    for (int sh = 0; sh < SHOT; ++sh) s += Z[(size_t)(sh * WAY + w) * DD + k];
    SL[(size_t)w * DD + k] = s;
    float m = s / 5.0f;
    mus[(size_t)w * DD + k] = m;
    musb[(size_t)w * DD + k] = f2bs(m);
    q += m * m;
  }
  red[tid] = q; __syncthreads();
  for (int o = 128; o > 0; o >>= 1) { if (tid < o) red[tid] += red[tid + o]; __syncthreads(); }
  if (tid == 0) musqP[(size_t)w * 256] = red[0];
  else musqP[(size_t)w * 256 + tid] = 0.f;
}

// ---- one-time: Zu -> bf16 row-major; launched twice (ubase 0 then 768) to sequence overlap ----
__global__ __launch_bounds__(256) void k_zb(const float* __restrict__ Z, short* __restrict__ Zb, int ubase) {
  size_t i0 = (size_t)ubase * DD + ((size_t)blockIdx.x * 256 + threadIdx.x) * 8;
  short8_t v;
  if (i0 < (size_t)N_U * DD) {
    const float* src = Z + (size_t)N_L * DD + i0;
    float4 a = *(const float4*)src;
    float4 b = *(const float4*)(src + 4);
    v[0] = f2bs(a.x); v[1] = f2bs(a.y); v[2] = f2bs(a.z); v[3] = f2bs(a.w);
    v[4] = f2bs(b.x); v[5] = f2bs(b.y); v[6] = f2bs(b.z); v[7] = f2bs(b.w);
  } else {
    v = (short8_t){0, 0, 0, 0, 0, 0, 0, 0};
  }
  *(short8_t*)(Zb + i0) = v;
}

// ---- one-time: Zu^T hi/lo bf16 (4096 x 1536, cols 1500..1535 zeroed) ----
__global__ __launch_bounds__(256) void k_zt(const float* __restrict__ Z, short* __restrict__ ZTH,
                                            short* __restrict__ ZTL) {
  __shared__ float tile[32][33];
  int k0 = blockIdx.x * 32, u0 = blockIdx.y * 32;
  int c = threadIdx.x & 31, r0 = threadIdx.x >> 5;
#pragma unroll
  for (int rr = 0; rr < 4; ++rr) {
    int r = r0 + rr * 8;
    int u = u0 + r;
    tile[r][c] = (u < N_U) ? Z[(size_t)(N_L + u) * DD + k0 + c] : 0.f;
  }
  __syncthreads();
#pragma unroll
  for (int rr = 0; rr < 4; ++rr) {
    int r = r0 + rr * 8;
    float v = tile[c][r];
    short hi = f2bs(v);
    ZTH[(size_t)(k0 + r) * PTS + u0 + c] = hi;
    ZTL[(size_t)(k0 + r) * PTS + u0 + c] = f2bs(v - bs2f(hi));
  }
}

// ---------------- GEMM1+expK fused (MFMA, 4-wave k-split): Kmat[u][w] = exp(-lam*dist) ------------
__global__ __launch_bounds__(256) void k_gemm1K(const short* __restrict__ Zb, const short* __restrict__ musb,
                                                const float* __restrict__ musqP, float* __restrict__ Kmat,
                                                unsigned* __restrict__ misc_u, float* __restrict__ colsP) {
  int tid = threadIdx.x;
  __shared__ float redA[4 * 7 * 4 * 64];   // 28 KB
  __shared__ float musq2[2][128];
  if (blockIdx.x == 0) {
    for (int z = tid; z < 768; z += 256) misc_u[z] = 0u;   // Ksum + cold barrier slots + ctr
    if (tid < 64)                                          // re-zero 2x32 exchange tags
      st_agent(colsP + (tid >> 5) * 4096 + (tid & 31) * 128 + 101, 0.f);
  }
  {
    int w = tid >> 1, half = tid & 1;
    if (w < WAY) {
      const float* mp = musqP + (size_t)w * 256 + half * 128;
      float q = 0.f;
#pragma unroll 4
      for (int bb = 0; bb < 128; bb += 4) {
        float4 v4 = *(const float4*)(mp + bb);
        q += (v4.x + v4.y) + (v4.z + v4.w);
      }
      musq2[half][w] = q;
    }
  }
  int wv = tid >> 6, l = tid & 63;
  int l15 = l & 15, quad = (l >> 4) & 3;
  int u0 = blockIdx.x * 16;
  f32x4 acc[7];
#pragma unroll
  for (int c = 0; c < 7; ++c) acc[c] = (f32x4){0.f, 0.f, 0.f, 0.f};

  const short* bp = Zb + (size_t)(u0 + l15) * DD + wv * 1024 + quad * 8;
  const short* ap = musb + (size_t)l15 * DD + wv * 1024 + quad * 8;
#pragma unroll 2
  for (int kc = 0; kc < 1024; kc += 32) {
    short8_t bf = *(const short8_t*)(bp + kc);
#pragma unroll
    for (int c = 0; c < 7; ++c) {
      short8_t af = *(const short8_t*)(ap + (size_t)c * 16 * DD + kc);
      acc[c] = __builtin_amdgcn_mfma_f32_16x16x32_bf16(af, bf, acc[c], 0, 0, 0);
    }
  }
#pragma unroll
  for (int c = 0; c < 7; ++c)
#pragma unroll
    for (int r = 0; r < 4; ++r)
      redA[((wv * 7 + c) * 4 + r) * 64 + l] = acc[c][r];
  __syncthreads();
  if (wv == 0) {
    int u = u0 + l15;
#pragma unroll
    for (int c = 0; c < 7; ++c)
#pragma unroll
      for (int r = 0; r < 4; ++r) {
        int base = (c * 4 + r) * 64 + l;
        float s = redA[base] + redA[base + 1792] + redA[base + 3584] + redA[base + 5376];
        int w = 16 * c + quad * 4 + r;
        if (w < WAY && u < N_U) {
          float d2 = 1.0f + (musq2[0][w] + musq2[1][w]) - 2.0f * s;
          Kmat[(size_t)u * WAY + w] = expf(-LAMF * sqrtf(fmaxf(d2, 1e-12f)));
        }
      }
  }
}

// ---------------- sinkhorn (32 blocks x 512, tagged-line exchange — R8-proven protocol) ----------
// Publish: data st_agent -> __syncthreads (per-wave vmcnt drain before s_barrier, R1-proven)
// -> tag store (slot 101, monotone t+1). Consume: wave-0 lanes poll the 32 tags, mirror to LDS
// flags + read err; fan-in threads spin on LDS flags and load each line as it arrives.
// Double-buffer safety: block posts t only after consuming t-1 (depth-2 argument as before).
// Tags zeroed by pow_norm (first launch) and gemm1K block 0 (between sink launches, stream-ordered).
__device__ __forceinline__ void gbar(unsigned* slots, unsigned t) {   // cold-epoch Ksum barrier only
  __syncthreads();
  if (threadIdx.x == 0) {
    asm volatile("s_waitcnt vmcnt(0) lgkmcnt(0)" ::: "memory");
    __hip_atomic_store(slots + (unsigned)blockIdx.x * 16, t, __ATOMIC_RELAXED, __HIP_MEMORY_SCOPE_AGENT);
  }
  if (threadIdx.x < SINK_BLOCKS) {
    while (__hip_atomic_load(slots + threadIdx.x * 16, __ATOMIC_ACQUIRE, __HIP_MEMORY_SCOPE_AGENT) < t)
      __builtin_amdgcn_s_sleep(1);
  }
  __syncthreads();
}

__global__ __launch_bounds__(SINK_T) void k_sink(const float* __restrict__ Kg,
                                                 short* __restrict__ PTH, short* __restrict__ PTL,
                                                 float* __restrict__ colsP, float* __restrict__ aG,
                                                 float* __restrict__ prevG, float* __restrict__ binit,
                                                 unsigned* __restrict__ misc_u, float* __restrict__ misc_f,
                                                 const int* __restrict__ labels, float* __restrict__ out,
                                                 int finalmode) {
  __shared__ float Kl[RPB * 100];                // 18.8 KB; stride 100 (=4 mod 32): f4 reads ~2-way
  __shared__ float4 bS4[25];
  __shared__ float a[RPB], aold[RPB], prevs[RPB];
  __shared__ float rerr[SINK_T];
  __shared__ float c2[800];                      // col partials [8 chunks][100]
  __shared__ float red[SINK_T];
  __shared__ float eSh;
  __shared__ int tagf[SINK_BLOCKS];              // LDS mirror of remote tags (monotone)
  float* bS = (float*)bS4;
  unsigned* slots = misc_u + 8;
  float* KsumG = misc_f + 3;
  int tid = threadIdx.x;
  int row0 = (int)blockIdx.x * RPB;
  int nrows = (blockIdx.x == SINK_BLOCKS - 1) ? (N_U - row0) : RPB;   // last: 43

  bool warm = (aG[row0] >= 0.f);                 // -1 sentinel on epoch 0 (uniform across blocks)
  if (tid < SINK_BLOCKS) tagf[tid] = 0;

  // ---- K load (contiguous float4); Ksum only on cold epoch ----
  float ks = 0.f;
  int n4 = nrows * 25;
  const float4* Ksrc = (const float4*)(Kg + (size_t)row0 * 100);
  for (int i = tid; i < n4; i += SINK_T) {
    float4 v = Ksrc[i];
    *(float4*)(&Kl[i * 4]) = v;
    ks += (v.x + v.y) + (v.z + v.w);
  }
  if (!warm) {                                   // warm epochs skip the tree reduce entirely
    red[tid] = ks; __syncthreads();
    for (int o = SINK_T / 2; o > 0; o >>= 1) { if (tid < o) red[tid] += red[tid + o]; __syncthreads(); }
    if (tid == 0) atomicAdd(KsumG, red[0]);
  }
  if (tid < WAY) bS[tid] = binit[tid];           // warm b (1.0 on epoch 0)

  if (!warm) gbar(slots, 1u);                    // cold only: need global Ksum before a-init
  float S = warm ? 1.f : ld_agent(KsumG);
  if (tid < nrows) {
    a[tid] = warm ? aG[row0 + tid] : (1.0f / S); // cold: folds K/K.sum() into a exactly
    prevs[tid] = warm ? prevG[row0 + tid] : 0.f;
  }

  bool conv = false;
  for (int t = 0; t < MAXIT; ++t) {
    float* cp = colsP + (t & 1) * 4096;
    __syncthreads();                             // #1 b stable (covers Kl/a/tagf init at t=0)
    if (tid < nrows) {                           // row pass: 1 row/thread (wave 0), float4 reads
      const float* kr = &Kl[tid * 100];
      float4 ac = {0.f, 0.f, 0.f, 0.f};
#pragma unroll
      for (int j4 = 0; j4 < 25; ++j4) {
        float4 bv = bS4[j4];
        float4 kv = *(const float4*)(kr + j4 * 4);
        ac.x = fmaf(kv.x, bv.x, ac.x); ac.y = fmaf(kv.y, bv.y, ac.y);
        ac.z = fmaf(kv.z, bv.z, ac.z); ac.w = fmaf(kv.w, bv.w, ac.w);
      }
      float rs = ((ac.x + ac.y) + (ac.z + ac.w)) * a[tid];
      rerr[tid] = fabsf(prevs[tid] - rs);
      aold[tid] = a[tid];
      a[tid] = a[tid] / rs;                      // speculative; rolled back on convergence
      prevs[tid] = rs;
    } else {
      rerr[tid] = 0.f;
    }
    __syncthreads();                             // #2 a, rerr stable
    if (tid < 200) {                             // col pass: 4 cols/thread (float4), 8 row-chunks
      int j4 = tid % 25, ch = tid / 25;
      int rlo = ch * CPR, rhi = rlo + CPR; if (rhi > nrows) rhi = nrows;
      float4 pa = {0.f, 0.f, 0.f, 0.f};
      for (int r = rlo; r < rhi; ++r) {
        float4 kv = *(const float4*)(&Kl[r * 100 + j4 * 4]);
        float av = a[r];
        pa.x = fmaf(kv.x, av, pa.x); pa.y = fmaf(kv.y, av, pa.y);
        pa.z = fmaf(kv.z, av, pa.z); pa.w = fmaf(kv.w, av, pa.w);
      }
      *(float4*)(&c2[ch * 100 + j4 * 4]) = pa;
    }
    if (tid >= 448) {                            // wave 7: block max-err -> line slot 100
      int t6 = tid & 63;
      float m = rerr[t6];
#pragma unroll
      for (int k = 1; k < 8; ++k) m = fmaxf(m, rerr[t6 + 64 * k]);
#pragma unroll
      for (int o = 32; o > 0; o >>= 1) m = fmaxf(m, __shfl_down(m, o));
      if (t6 == 0) st_agent(cp + (unsigned)blockIdx.x * 128 + 100, m);
    }
    __syncthreads();                             // #3 c2 stable
    if (tid < WAY) {
      float s = ((c2[tid] + c2[100 + tid]) + (c2[200 + tid] + c2[300 + tid])) +
                ((c2[400 + tid] + c2[500 + tid]) + (c2[600 + tid] + c2[700 + tid]));
      st_agent(cp + (unsigned)blockIdx.x * 128 + tid, s);
    }
    __syncthreads();                             // #4 all line stores drained at LLC (vmcnt drain)
    if (tid == 0)
      __hip_atomic_store((unsigned*)(cp + (unsigned)blockIdx.x * 128 + 101), (unsigned)(t + 1),
                         __ATOMIC_RELAXED, __HIP_MEMORY_SCOPE_AGENT);
    // consume: lanes 0-31 poll remote tags, mirror to LDS, read err; fan-in overlaps with arrival
    float epoll = 0.f;
    if (tid < SINK_BLOCKS) {
      const unsigned* tp = (const unsigned*)(cp + tid * 128 + 101);
      while (__hip_atomic_load(tp, __ATOMIC_ACQUIRE, __HIP_MEMORY_SCOPE_AGENT) < (unsigned)(t + 1))
        __builtin_amdgcn_s_sleep(1);
      __hip_atomic_store(&tagf[tid], t + 1, __ATOMIC_RELEASE, __HIP_MEMORY_SCOPE_WORKGROUP);
      epoll = ld_agent(cp + tid * 128 + 100);
    }
    if (tid < 64) {
      float e = epoll;                           // lanes 32-63 contribute 0 (errors >= 0)
#pragma unroll
      for (int o = 16; o > 0; o >>= 1) e = fmaxf(e, __shfl_down(e, o));
      if (tid == 0) eSh = e;
    }
    float bnew = 0.f;
    if (tid >= 256 && tid < 256 + WAY) {         // waves 4-5: per-line load as soon as its tag lands
      int j = tid - 256;
      float s = 0.f;
#pragma unroll
      for (int sb = 0; sb < SINK_BLOCKS; ++sb) {
        while (__hip_atomic_load(&tagf[sb], __ATOMIC_ACQUIRE, __HIP_MEMORY_SCOPE_WORKGROUP) < t + 1)
          __builtin_amdgcn_s_sleep(1);
        s += ld_agent(cp + sb * 128 + j);
      }
      bnew = (float)NQ / s;
    }
    __syncthreads();                             // #5 eSh stable, consumption complete
    if (eSh <= EPSF) { conv = true; break; }     // b intentionally NOT updated on converge
    if (tid >= 256 && tid < 256 + WAY) bS[tid - 256] = bnew;
  }
  __syncthreads();

  if (finalmode) {
    // fused k_final: fp32 logP directly from LDS state + per-row argmax
    for (int idx = tid; idx < nrows * WAY; idx += SINK_T) {
      int r = idx / WAY, j = idx - r * WAY;
      float av = conv ? aold[r] : a[r];
      float p = av * Kl[r * 100 + j] * bS[j];
      out[(size_t)(row0 + r) * WAY + j] = logf(p + 1e-5f);
    }
    if (tid < nrows) {
      const float* kr = &Kl[tid * 100];
      int am = 0; float bv = kr[0] * bS[0];      // argmax invariant to positive row scale av
      for (int j = 1; j < WAY; ++j) { float p = kr[j] * bS[j]; if (p > bv) { bv = p; am = j; } }
      if (am == labels[N_L + row0 + tid]) atomicAdd(misc_u + 5, 1u);
    }
    return;
  }

  // persist warm-start state for next epoch
  if (tid < nrows) {
    float af = conv ? aold[tid] : a[tid];
    aG[row0 + tid] = af;
    prevG[row0 + tid] = prevs[tid];
  }
  if (blockIdx.x == 0 && tid < WAY) binit[tid] = bS[tid];
  // P^T hi/lo bf16 (A-operand for gemm2), coalesced in u (pad cols zeroed once in musinit)
  for (int idx = tid; idx < WAY * nrows; idx += SINK_T) {
    int j = idx / nrows; int r = idx - j * nrows;
    float av = conv ? aold[r] : a[r];
    float p = av * Kl[r * 100 + j] * bS[j];
    short hi = f2bs(p);
    PTH[(size_t)j * PTS + row0 + r] = hi;
    PTL[(size_t)j * PTS + row0 + r] = f2bs(p - bs2f(hi));
  }
}

// ---------------- GEMM2 (MFMA, 3-term, u-split partials; 2048 waves — R1/R4-proven) -------------
__global__ __launch_bounds__(64) void k_gemm2(const short* __restrict__ PTH, const short* __restrict__ PTL,
                                              const short* __restrict__ ZTH, const short* __restrict__ ZTL,
                                              float* __restrict__ CPp) {
  int l = threadIdx.x, l15 = l & 15, quad = l >> 4;
  int k0 = blockIdx.x * 16;                      // 256 k-tiles
  int us = blockIdx.y;                           // 8 u-splits
  int kcb = us * 192;
  int kce = (us == 7) ? 1504 : kcb + 192;
  f32x4 acc[7];
#pragma unroll
  for (int c = 0; c < 7; ++c) acc[c] = (f32x4){0.f, 0.f, 0.f, 0.f};
  size_t aoff = (size_t)l15 * PTS + quad * 8;
  const short* bph = ZTH + (size_t)(k0 + l15) * PTS + quad * 8;
  const short* bpl = ZTL + (size_t)(k0 + l15) * PTS + quad * 8;
  for (int kc = kcb; kc < kce; kc += 32) {
    short8_t bh = *(const short8_t*)(bph + kc);
    short8_t bl = *(const short8_t*)(bpl + kc);
#pragma unroll
    for (int c = 0; c < 7; ++c) {
      short8_t ah = *(const short8_t*)(PTH + aoff + (size_t)c * 16 * PTS + kc);
      short8_t al = *(const short8_t*)(PTL + aoff + (size_t)c * 16 * PTS + kc);
      acc[c] = __builtin_amdgcn_mfma_f32_16x16x32_bf16(ah, bh, acc[c], 0, 0, 0);
      acc[c] = __builtin_amdgcn_mfma_f32_16x16x32_bf16(al, bh, acc[c], 0, 0, 0);
      acc[c] = __builtin_amdgcn_mfma_f32_16x16x32_bf16(ah, bl, acc[c], 0, 0, 0);
    }
  }
  float* dst = CPp + (size_t)us * CPS;
#pragma unroll
  for (int c = 0; c < 7; ++c)
#pragma unroll
    for (int r = 0; r < 4; ++r) {
      int w = 16 * c + quad * 4 + r;
      if (w < WAY) dst[(size_t)w * DD + k0 + l15] = acc[c][r];
    }
}

// ---------------- mus update + musq (reduces 8 CP partials; k-split grid (100,4) — R1/R4-proven) -
__global__ __launch_bounds__(256) void k_musup(const float* __restrict__ musR, const float* __restrict__ SL,
                                               const float* __restrict__ CPp, float* __restrict__ musW,
                                               short* __restrict__ musb, float* __restrict__ musqP) {
  int w = blockIdx.x, tid = threadIdx.x;
  int kb = blockIdx.y * 1024;
  __shared__ float red[256];
  float q = 0.f;
  for (int k = kb + tid; k < kb + 1024; k += 256) {
    size_t o = (size_t)w * DD + k;
    float c = 0.f;
#pragma unroll
    for (int s = 0; s < 8; ++s) c += CPp[(size_t)s * CPS + o];
    float emus = (SL[o] + c) / 20.0f;   // p.sum(0) == 5 + 15 exactly
    float m = musR[o];
    float v = m + 0.2f * (emus - m);
    musW[o] = v;
    musb[o] = f2bs(v);
    q += v * v;
  }
  red[tid] = q; __syncthreads();
  for (int o = 128; o > 0; o >>= 1) { if (tid < o) red[tid] += red[tid + o]; __syncthreads(); }
  if (tid == 0) musqP[(size_t)w * 256 + blockIdx.y] = red[0];   // slots 4..255 stay zero (musinit)
}

__global__ void k_acc(const unsigned* __restrict__ ctr, float* __restrict__ out) {
  if (threadIdx.x == 0) out[N_U * WAY] = (float)(*ctr) / 1500.0f;
}

// ---------------- host ----------------
extern "C" void kernel_launch(void* const* d_in, const int* in_sizes, int n_in,
                              void* d_out, int out_size, void* d_ws, size_t ws_size,
                              hipStream_t stream) {
  const float* X = (const float*)d_in[0];
  const int* labels = (const int*)d_in[1];
  float* out = (float*)d_out;
  float* ws = (float*)d_ws;

  float* Z     = ws + OFF_Z;
  short* Zb    = (short*)(ws + OFF_Z);       // overlays Z rows 0..768 (sequenced via 2 launches)
  float* CPp   = ws + OFF_CPP;               // dead fp32 Z region after zb
  float* meanL = ws + OFF_MEANL;
  float* meanU = ws + OFF_MEANU;
  float* SL    = ws + OFF_SL;
  float* musA  = ws + OFF_MUSA;
  float* musB  = ws + OFF_MUSB;
  float* musqP = ws + OFF_MUSQP;
  short* musb16 = (short*)(ws + OFF_MUSB16);
  short* PTH   = (short*)(ws + OFF_PTH);
  short* PTL   = (short*)(ws + OFF_PTL);
  float* Kmat  = ws + OFF_KMAT;
  float* colsP = ws + OFF_COLS;
  float* misc_f = ws + OFF_MISC;
  unsigned* misc_u = (unsigned*)(ws + OFF_MISC);
  short* ZTH   = (short*)(ws + OFF_ZUT);
  short* ZTL   = (short*)(ws + OFF_ZUTL);
  float* aG    = ws + OFF_AG;
  float* prevG = ws + OFF_PREVG;
  float* binit = ws + OFF_BINIT;

  k_pow_norm<<<N_TOT, 256, 0, stream>>>(X, Z, meanL, misc_u, aG, colsP);
  k_colmeans<<<dim3(16, 25), 256, 0, stream>>>(Z, meanL, meanU);
  k_center<<<N_TOT, 256, 0, stream>>>(Z, meanL, meanU);
  k_musinit<<<WAY, 256, 0, stream>>>(Z, SL, musA, musb16, musqP, binit, PTH, PTL);
  k_zt<<<dim3(128, 48), 256, 0, stream>>>(Z, ZTH, ZTL);
  k_zb<<<1536, 256, 0, stream>>>(Z, Zb, 0);    // lo half: no src/dst overlap
  k_zb<<<1536, 256, 0, stream>>>(Z, Zb, 768);  // hi half: overlaps only consumed sources

  float* musR = musA;
  float* musW = musB;
  for (int e = 0; e < 20; ++e) {
    k_gemm1K<<<96, 256, 0, stream>>>(Zb, musb16, musqP, Kmat, misc_u, colsP);
    k_sink<<<SINK_BLOCKS, SINK_T, 0, stream>>>(Kmat, PTH, PTL, colsP, aG, prevG, binit, misc_u, misc_f,
                                               labels, out, 0);
    k_gemm2<<<dim3(256, 8), 64, 0, stream>>>(PTH, PTL, ZTH, ZTL, CPp);
    k_musup<<<dim3(WAY, 4), 256, 0, stream>>>(musR, SL, CPp, musW, musb16, musqP);
    float* tmp = musR; musR = musW; musW = tmp;
  }
  k_gemm1K<<<96, 256, 0, stream>>>(Zb, musb16, musqP, Kmat, misc_u, colsP);
  k_sink<<<SINK_BLOCKS, SINK_T, 0, stream>>>(Kmat, PTH, PTL, colsP, aG, prevG, binit, misc_u, misc_f,
                                             labels, out, 1);
  k_acc<<<1, 64, 0, stream>>>(misc_u + 5, out);
}

// Round 10
// 1963.066 us; speedup vs baseline: 1.0180x; 1.0180x over previous
//
#include <hip/hip_runtime.h>

#define WAY   100
#define SHOT  5
#define NQ    15
#define DD    4096
#define N_L   500
#define N_U   1500
#define N_TOT 2000
#define LAMF  10.0f
#define EPSF  1e-6f
#define MAXIT 1000

// ---- workspace layout (float offsets) ----
#define OFF_Z      0u          // Z fp32 2000*4096. After preproc: Zb bf16 (3072000 fl) at 0,
                               //   CPp (8*409600 fl) at 3145728 (dead fp32 Z region)
#define OFF_CPP    3145728u
#define OFF_MEANL  8192000u    // 4096 col sums
#define OFF_MEANU  8196096u    // 4096
#define OFF_SL     8200192u    // 100*4096
#define OFF_MUSA   8609792u    // 112*4096
#define OFF_MUSB   9068544u    // 112*4096
#define OFF_MUSQP  9527296u    // 100*256 musq partials [w][0..3] from musup, rest zero (musinit)
#define OFF_MUSB16 9552896u    // bf16 mus 112*4096 sh = 229376 fl
#define OFF_PTH    9782272u    // bf16 P^T hi 112*1536 sh = 86016 fl
#define OFF_PTL    9868288u    // bf16 P^T lo 112*1536 sh = 86016 fl
#define OFF_KMAT   9954304u    // 150000 (+pad)
#define OFF_COLS   10104320u   // colsP lines [2][16][128] = 4096 fl (double-buffered)
#define OFF_MISC   10113920u   // [3]=Ksum(f) [5]=ctr [8+16b]=barrier slots (b<16)
#define OFF_ZUT    10114688u   // bf16 Zu^T hi 4096*1536 sh = 3145728 fl
#define OFF_ZUTL   13260416u   // bf16 Zu^T lo 4096*1536 sh = 3145728 fl -> ends 16406144
#define OFF_AG     16406144u   // warm-start a, 1504 fl (sentinel -1 = cold)
#define OFF_PREVG  16407680u   // warm-start prev rowsums, 1504 fl
#define OFF_BINIT  16409216u   // warm-start b, 128 fl

#define SINK_BLOCKS 16         // closed curve: 8=2100, 16=1964-1972, 32=1998 -> 16 is the optimum
#define SINK_T 512
#define RPB 94                 // rows per sinkhorn block (16*94 = 1504; last block 90)
#define CPR 12                 // rows per col-pass chunk (8 chunks cover 94)
#define PTS 1536               // P^T / ZuT row stride (shorts)
#define CPS 409600u            // CP partial stride (100*4096)

typedef __attribute__((ext_vector_type(8))) short short8_t;
typedef __attribute__((ext_vector_type(4))) float f32x4;

__device__ __forceinline__ short f2bs(float f) {   // fp32 -> bf16 RNE
  unsigned u = __float_as_uint(f);
  unsigned r = (u + 0x7FFFu + ((u >> 16) & 1u)) >> 16;
  return (short)r;
}
__device__ __forceinline__ float bs2f(short s) {
  return __uint_as_float(((unsigned)(unsigned short)s) << 16);
}

// relaxed agent-scope (LLC, sc1) atomics: cross-XCD exchange without wbl2/inv fences (R1-proven)
__device__ __forceinline__ float ld_agent(const float* p) {
  return __hip_atomic_load(p, __ATOMIC_RELAXED, __HIP_MEMORY_SCOPE_AGENT);
}
__device__ __forceinline__ void st_agent(float* p, float v) {
  __hip_atomic_store(p, v, __ATOMIC_RELAXED, __HIP_MEMORY_SCOPE_AGENT);
}

// ---------------- preprocessing ----------------
__global__ __launch_bounds__(256) void k_pow_norm(const float* __restrict__ X, float* __restrict__ Z,
                                                  float* __restrict__ msums, unsigned* __restrict__ misc_u,
                                                  float* __restrict__ aG) {
  int i = blockIdx.x, tid = threadIdx.x;
  __shared__ float red[256];
  if (i < 32) msums[i * 256 + tid] = 0.f;
  if (i == 32) { misc_u[tid] = 0u; misc_u[tid + 256] = 0u; misc_u[tid + 512] = 0u; }
  if (i == 33) { for (int z = tid; z < 1504; z += 256) aG[z] = -1.f; }   // cold sentinel
  const float* x = X + (size_t)i * DD;
  float s = 0.f;
  for (int k = tid; k < DD; k += 256) s += x[k] + 1e-6f;
  red[tid] = s; __syncthreads();
  for (int o = 128; o > 0; o >>= 1) { if (tid < o) red[tid] += red[tid + o]; __syncthreads(); }
  float inv = 1.0f / fmaxf(sqrtf(red[0]), 1e-12f);
  float* z = Z + (size_t)i * DD;
  for (int k = tid; k < DD; k += 256) z[k] = sqrtf(x[k] + 1e-6f) * inv;
}

__global__ __launch_bounds__(256) void k_colmeans(const float* __restrict__ Z, float* __restrict__ mLs,
                                                  float* __restrict__ mUs) {
  int k = blockIdx.x * 256 + threadIdx.x;
  int r0 = blockIdx.y * 80;
  float sL = 0.f, sU = 0.f;
  for (int r = r0; r < r0 + 80; ++r) {
    float v = Z[(size_t)r * DD + k];
    if (r < N_L) sL += v; else sU += v;
  }
  if (r0 < N_L) atomicAdd(&mLs[k], sL);
  if (r0 + 80 > N_L) atomicAdd(&mUs[k], sU);
}

__global__ __launch_bounds__(256) void k_center(float* __restrict__ Z, const float* __restrict__ mLs,
                                                const float* __restrict__ mUs) {
  int i = blockIdx.x, tid = threadIdx.x;
  __shared__ float red[256];
  const float* m = (i < N_L) ? mLs : mUs;
  const float scale = (i < N_L) ? (1.0f / 500.0f) : (1.0f / 1500.0f);
  float* z = Z + (size_t)i * DD;
  float s = 0.f;
  for (int k = tid; k < DD; k += 256) { float v = z[k] - m[k] * scale; s += v * v; }
  red[tid] = s; __syncthreads();
  for (int o = 128; o > 0; o >>= 1) { if (tid < o) red[tid] += red[tid + o]; __syncthreads(); }
  float inv = 1.0f / fmaxf(sqrtf(red[0]), 1e-12f);
  for (int k = tid; k < DD; k += 256) z[k] = (z[k] - m[k] * scale) * inv;
}

// musinit also one-time zeroes PT pad cols 1500..1503 (rows 0..99); sink never writes them.
__global__ __launch_bounds__(256) void k_musinit(const float* __restrict__ Z, float* __restrict__ SL,
                                                 float* __restrict__ mus, short* __restrict__ musb,
                                                 float* __restrict__ musqP, float* __restrict__ binit,
                                                 short* __restrict__ PTH, short* __restrict__ PTL) {
  int w = blockIdx.x, tid = threadIdx.x;
  __shared__ float red[256];
  if (tid == 0) binit[w] = 1.0f;
  if (tid >= 4 && tid < 8) PTH[(size_t)w * PTS + 1500 + (tid - 4)] = 0;
  if (tid >= 8 && tid < 12) PTL[(size_t)w * PTS + 1500 + (tid - 8)] = 0;
  float q = 0.f;
  for (int k = tid; k < DD; k += 256) {
    float s = 0.f;
    for (int sh = 0; sh < SHOT; ++sh) s += Z[(size_t)(sh * WAY + w) * DD + k];
    SL[(size_t)w * DD + k] = s;
    float m = s / 5.0f;
    mus[(size_t)w * DD + k] = m;
    musb[(size_t)w * DD + k] = f2bs(m);
    q += m * m;
  }
  red[tid] = q; __syncthreads();
  for (int o = 128; o > 0; o >>= 1) { if (tid < o) red[tid] += red[tid + o]; __syncthreads(); }
  if (tid == 0) musqP[(size_t)w * 256] = red[0];
  else musqP[(size_t)w * 256 + tid] = 0.f;
}

// ---- one-time: Zu -> bf16 row-major; launched twice (ubase 0 then 768) to sequence overlap ----
__global__ __launch_bounds__(256) void k_zb(const float* __restrict__ Z, short* __restrict__ Zb, int ubase) {
  size_t i0 = (size_t)ubase * DD + ((size_t)blockIdx.x * 256 + threadIdx.x) * 8;
  short8_t v;
  if (i0 < (size_t)N_U * DD) {
    const float* src = Z + (size_t)N_L * DD + i0;
    float4 a = *(const float4*)src;
    float4 b = *(const float4*)(src + 4);
    v[0] = f2bs(a.x); v[1] = f2bs(a.y); v[2] = f2bs(a.z); v[3] = f2bs(a.w);
    v[4] = f2bs(b.x); v[5] = f2bs(b.y); v[6] = f2bs(b.z); v[7] = f2bs(b.w);
  } else {
    v = (short8_t){0, 0, 0, 0, 0, 0, 0, 0};
  }
  *(short8_t*)(Zb + i0) = v;
}

// ---- one-time: Zu^T hi/lo bf16 (4096 x 1536, cols 1500..1535 zeroed) ----
__global__ __launch_bounds__(256) void k_zt(const float* __restrict__ Z, short* __restrict__ ZTH,
                                            short* __restrict__ ZTL) {
  __shared__ float tile[32][33];
  int k0 = blockIdx.x * 32, u0 = blockIdx.y * 32;
  int c = threadIdx.x & 31, r0 = threadIdx.x >> 5;
#pragma unroll
  for (int rr = 0; rr < 4; ++rr) {
    int r = r0 + rr * 8;
    int u = u0 + r;
    tile[r][c] = (u < N_U) ? Z[(size_t)(N_L + u) * DD + k0 + c] : 0.f;
  }
  __syncthreads();
#pragma unroll
  for (int rr = 0; rr < 4; ++rr) {
    int r = r0 + rr * 8;
    float v = tile[c][r];
    short hi = f2bs(v);
    ZTH[(size_t)(k0 + r) * PTS + u0 + c] = hi;
    ZTL[(size_t)(k0 + r) * PTS + u0 + c] = f2bs(v - bs2f(hi));
  }
}

// ---------------- GEMM1+expK fused (MFMA, 4-wave k-split): Kmat[u][w] = exp(-lam*dist) ------------
__global__ __launch_bounds__(256) void k_gemm1K(const short* __restrict__ Zb, const short* __restrict__ musb,
                                                const float* __restrict__ musqP, float* __restrict__ Kmat,
                                                unsigned* __restrict__ misc_u) {
  int tid = threadIdx.x;
  __shared__ float redA[4 * 7 * 4 * 64];   // 28 KB
  __shared__ float musq2[2][128];
  if (blockIdx.x == 0) {
    for (int z = tid; z < 768; z += 256) misc_u[z] = 0u;   // Ksum + barrier slots + ctr
  }
  {
    int w = tid >> 1, half = tid & 1;
    if (w < WAY) {
      const float* mp = musqP + (size_t)w * 256 + half * 128;
      float q = 0.f;
#pragma unroll 4
      for (int bb = 0; bb < 128; bb += 4) {
        float4 v4 = *(const float4*)(mp + bb);
        q += (v4.x + v4.y) + (v4.z + v4.w);
      }
      musq2[half][w] = q;
    }
  }
  int wv = tid >> 6, l = tid & 63;
  int l15 = l & 15, quad = (l >> 4) & 3;
  int u0 = blockIdx.x * 16;
  f32x4 acc[7];
#pragma unroll
  for (int c = 0; c < 7; ++c) acc[c] = (f32x4){0.f, 0.f, 0.f, 0.f};

  const short* bp = Zb + (size_t)(u0 + l15) * DD + wv * 1024 + quad * 8;
  const short* ap = musb + (size_t)l15 * DD + wv * 1024 + quad * 8;
#pragma unroll 2
  for (int kc = 0; kc < 1024; kc += 32) {
    short8_t bf = *(const short8_t*)(bp + kc);
#pragma unroll
    for (int c = 0; c < 7; ++c) {
      short8_t af = *(const short8_t*)(ap + (size_t)c * 16 * DD + kc);
      acc[c] = __builtin_amdgcn_mfma_f32_16x16x32_bf16(af, bf, acc[c], 0, 0, 0);
    }
  }
#pragma unroll
  for (int c = 0; c < 7; ++c)
#pragma unroll
    for (int r = 0; r < 4; ++r)
      redA[((wv * 7 + c) * 4 + r) * 64 + l] = acc[c][r];
  __syncthreads();
  if (wv == 0) {
    int u = u0 + l15;
#pragma unroll
    for (int c = 0; c < 7; ++c)
#pragma unroll
      for (int r = 0; r < 4; ++r) {
        int base = (c * 4 + r) * 64 + l;
        float s = redA[base] + redA[base + 1792] + redA[base + 3584] + redA[base + 5376];
        int w = 16 * c + quad * 4 + r;
        if (w < WAY && u < N_U) {
          float d2 = 1.0f + (musq2[0][w] + musq2[1][w]) - 2.0f * s;
          Kmat[(size_t)u * WAY + w] = expf(-LAMF * sqrtf(fmaxf(d2, 1e-12f)));
        }
      }
  }
}

// ---------------- sinkhorn (16 blocks x 512, R1/R4-proven agent-scope exchange) ----------------
// Ticket barrier: __syncthreads drains each wave's vmcnt before s_barrier, so all sc1 partial
// stores are at LLC before thread 0's ticket store; consumers use sc1 loads.
// Slots are re-zeroed by the following k_gemm1K (block 0) before the next sink launch.
// Structural floor note (R7-R9): three exchange protocols (ticket, tagged-line) and three
// participant counts (8/16/32) all measure 1964-2100 us; the per-iteration all-to-all is pinned
// at the cross-XCD LLC round-trip latency, not protocol or per-CU work.
__device__ __forceinline__ void gbar(unsigned* slots, unsigned t) {
  __syncthreads();
  if (threadIdx.x == 0) {
    asm volatile("s_waitcnt vmcnt(0) lgkmcnt(0)" ::: "memory");
    __hip_atomic_store(slots + (unsigned)blockIdx.x * 16, t, __ATOMIC_RELAXED, __HIP_MEMORY_SCOPE_AGENT);
  }
  if (threadIdx.x < SINK_BLOCKS) {
    while (__hip_atomic_load(slots + threadIdx.x * 16, __ATOMIC_ACQUIRE, __HIP_MEMORY_SCOPE_AGENT) < t)
      __builtin_amdgcn_s_sleep(1);
  }
  __syncthreads();
}

__global__ __launch_bounds__(SINK_T) void k_sink(const float* __restrict__ Kg,
                                                 short* __restrict__ PTH, short* __restrict__ PTL,
                                                 float* __restrict__ colsP, float* __restrict__ aG,
                                                 float* __restrict__ prevG, float* __restrict__ binit,
                                                 unsigned* __restrict__ misc_u, float* __restrict__ misc_f,
                                                 const int* __restrict__ labels, float* __restrict__ out,
                                                 int finalmode) {
  __shared__ float Kl[RPB * 100];                // 37.6 KB; stride 100 (=4 mod 32): f4 reads ~2-way
  __shared__ float4 bS4[25];
  __shared__ float a[RPB], aold[RPB], prevs[RPB];
  __shared__ float rerr[SINK_T];
  __shared__ float c2[800];                      // col partials [8 chunks][100]
  __shared__ float red[SINK_T];
  __shared__ float eSh;
  float* bS = (float*)bS4;
  unsigned* slots = misc_u + 8;
  float* KsumG = misc_f + 3;
  int tid = threadIdx.x;
  int row0 = (int)blockIdx.x * RPB;
  int nrows = (blockIdx.x == SINK_BLOCKS - 1) ? (N_U - row0) : RPB;   // last: 90

  bool warm = (aG[row0] >= 0.f);                 // -1 sentinel on epoch 0 (uniform across blocks)

  // ---- K load (contiguous float4); Ksum only on cold epoch ----
  float ks = 0.f;
  int n4 = nrows * 25;
  const float4* Ksrc = (const float4*)(Kg + (size_t)row0 * 100);
  for (int i = tid; i < n4; i += SINK_T) {
    float4 v = Ksrc[i];
    *(float4*)(&Kl[i * 4]) = v;
    ks += (v.x + v.y) + (v.z + v.w);
  }
  if (!warm) {                                   // warm epochs skip the tree reduce entirely
    red[tid] = ks; __syncthreads();
    for (int o = SINK_T / 2; o > 0; o >>= 1) { if (tid < o) red[tid] += red[tid + o]; __syncthreads(); }
    if (tid == 0) atomicAdd(KsumG, red[0]);
  }
  if (tid < WAY) bS[tid] = binit[tid];           // warm b (1.0 on epoch 0)

  unsigned bt = 0;
  if (!warm) { ++bt; gbar(slots, bt); }          // cold only: need global Ksum before a-init
  float S = warm ? 1.f : ld_agent(KsumG);
  if (tid < nrows) {
    a[tid] = warm ? aG[row0 + tid] : (1.0f / S); // cold: folds K/K.sum() into a exactly
    prevs[tid] = warm ? prevG[row0 + tid] : 0.f;
  }

  bool conv = false;
  for (int t = 0; t < MAXIT; ++t) {
    float* cp = colsP + (t & 1) * 2048;
    __syncthreads();                             // #1 b stable (also covers Kl/a init at t=0)
    if (tid < nrows) {                           // row pass: 1 row/thread (waves 0-1), float4 reads
      const float* kr = &Kl[tid * 100];
      float4 ac = {0.f, 0.f, 0.f, 0.f};
#pragma unroll
      for (int j4 = 0; j4 < 25; ++j4) {
        float4 bv = bS4[j4];
        float4 kv = *(const float4*)(kr + j4 * 4);
        ac.x = fmaf(kv.x, bv.x, ac.x); ac.y = fmaf(kv.y, bv.y, ac.y);
        ac.z = fmaf(kv.z, bv.z, ac.z); ac.w = fmaf(kv.w, bv.w, ac.w);
      }
      float rs = ((ac.x + ac.y) + (ac.z + ac.w)) * a[tid];
      rerr[tid] = fabsf(prevs[tid] - rs);
      aold[tid] = a[tid];
      a[tid] = a[tid] / rs;                      // speculative; rolled back on convergence
      prevs[tid] = rs;
    } else {
      rerr[tid] = 0.f;
    }
    __syncthreads();                             // #2 a, rerr stable
    if (tid < 200) {                             // col pass: 4 cols/thread (float4), 8 row-chunks
      int j4 = tid % 25, ch = tid / 25;
      int rlo = ch * CPR, rhi = rlo + CPR; if (rhi > nrows) rhi = nrows;
      float4 pa = {0.f, 0.f, 0.f, 0.f};
      for (int r = rlo; r < rhi; ++r) {
        float4 kv = *(const float4*)(&Kl[r * 100 + j4 * 4]);
        float av = a[r];
        pa.x = fmaf(kv.x, av, pa.x); pa.y = fmaf(kv.y, av, pa.y);
        pa.z = fmaf(kv.z, av, pa.z); pa.w = fmaf(kv.w, av, pa.w);
      }
      *(float4*)(&c2[ch * 100 + j4 * 4]) = pa;
    }
    if (tid >= 448) {                            // wave 7: block max-err -> line slot 100
      int t6 = tid & 63;
      float m = rerr[t6];
#pragma unroll
      for (int k = 1; k < 8; ++k) m = fmaxf(m, rerr[t6 + 64 * k]);
#pragma unroll
      for (int o = 32; o > 0; o >>= 1) m = fmaxf(m, __shfl_down(m, o));
      if (t6 == 0) st_agent(cp + (unsigned)blockIdx.x * 128 + 100, m);
    }
    __syncthreads();                             // #3 c2 stable
    if (tid < WAY) {
      float s = ((c2[tid] + c2[100 + tid]) + (c2[200 + tid] + c2[300 + tid])) +
                ((c2[400 + tid] + c2[500 + tid]) + (c2[600 + tid] + c2[700 + tid]));
      st_agent(cp + (unsigned)blockIdx.x * 128 + tid, s);
    }
    ++bt;
    gbar(slots, bt);
    // overlap: waves 4-5 pull 16 col-partial lines while wave 0 pulls the 16 error slots
    float bnew = 0.f;
    if (tid >= 256 && tid < 256 + WAY) {
      int j = tid - 256;
      float s = 0.f;
#pragma unroll
      for (int sb = 0; sb < SINK_BLOCKS; ++sb) s += ld_agent(cp + sb * 128 + j);
      bnew = (float)NQ / s;
    }
    if (tid < 64) {
      float e = (tid < SINK_BLOCKS) ? ld_agent(cp + tid * 128 + 100) : 0.f;
#pragma unroll
      for (int o = 8; o > 0; o >>= 1) e = fmaxf(e, __shfl_down(e, o));
      if (tid == 0) eSh = e;
    }
    __syncthreads();
    if (eSh <= EPSF) { conv = true; break; }     // b intentionally NOT updated on converge
    if (tid >= 256 && tid < 256 + WAY) bS[tid - 256] = bnew;
  }
  __syncthreads();

  if (finalmode) {
    // fused k_final: fp32 logP directly from LDS state + per-row argmax
    for (int idx = tid; idx < nrows * WAY; idx += SINK_T) {
      int r = idx / WAY, j = idx - r * WAY;
      float av = conv ? aold[r] : a[r];
      float p = av * Kl[r * 100 + j] * bS[j];
      out[(size_t)(row0 + r) * WAY + j] = logf(p + 1e-5f);
    }
    if (tid < nrows) {
      const float* kr = &Kl[tid * 100];
      int am = 0; float bv = kr[0] * bS[0];      // argmax invariant to positive row scale av
      for (int j = 1; j < WAY; ++j) { float p = kr[j] * bS[j]; if (p > bv) { bv = p; am = j; } }
      if (am == labels[N_L + row0 + tid]) atomicAdd(misc_u + 5, 1u);
    }
    return;
  }

  // persist warm-start state for next epoch
  if (tid < nrows) {
    float af = conv ? aold[tid] : a[tid];
    aG[row0 + tid] = af;
    prevG[row0 + tid] = prevs[tid];
  }
  if (blockIdx.x == 0 && tid < WAY) binit[tid] = bS[tid];
  // P^T hi/lo bf16 (A-operand for gemm2), coalesced in u (pad cols zeroed once in musinit)
  for (int idx = tid; idx < WAY * nrows; idx += SINK_T) {
    int j = idx / nrows; int r = idx - j * nrows;
    float av = conv ? aold[r] : a[r];
    float p = av * Kl[r * 100 + j] * bS[j];
    short hi = f2bs(p);
    PTH[(size_t)j * PTS + row0 + r] = hi;
    PTL[(size_t)j * PTS + row0 + r] = f2bs(p - bs2f(hi));
  }
}

// ---------------- GEMM2 (MFMA, 3-term, u-split partials; 2048 waves — R1/R4-proven) -------------
__global__ __launch_bounds__(64) void k_gemm2(const short* __restrict__ PTH, const short* __restrict__ PTL,
                                              const short* __restrict__ ZTH, const short* __restrict__ ZTL,
                                              float* __restrict__ CPp) {
  int l = threadIdx.x, l15 = l & 15, quad = l >> 4;
  int k0 = blockIdx.x * 16;                      // 256 k-tiles
  int us = blockIdx.y;                           // 8 u-splits
  int kcb = us * 192;
  int kce = (us == 7) ? 1504 : kcb + 192;
  f32x4 acc[7];
#pragma unroll
  for (int c = 0; c < 7; ++c) acc[c] = (f32x4){0.f, 0.f, 0.f, 0.f};
  size_t aoff = (size_t)l15 * PTS + quad * 8;
  const short* bph = ZTH + (size_t)(k0 + l15) * PTS + quad * 8;
  const short* bpl = ZTL + (size_t)(k0 + l15) * PTS + quad * 8;
  for (int kc = kcb; kc < kce; kc += 32) {
    short8_t bh = *(const short8_t*)(bph + kc);
    short8_t bl = *(const short8_t*)(bpl + kc);
#pragma unroll
    for (int c = 0; c < 7; ++c) {
      short8_t ah = *(const short8_t*)(PTH + aoff + (size_t)c * 16 * PTS + kc);
      short8_t al = *(const short8_t*)(PTL + aoff + (size_t)c * 16 * PTS + kc);
      acc[c] = __builtin_amdgcn_mfma_f32_16x16x32_bf16(ah, bh, acc[c], 0, 0, 0);
      acc[c] = __builtin_amdgcn_mfma_f32_16x16x32_bf16(al, bh, acc[c], 0, 0, 0);
      acc[c] = __builtin_amdgcn_mfma_f32_16x16x32_bf16(ah, bl, acc[c], 0, 0, 0);
    }
  }
  float* dst = CPp + (size_t)us * CPS;
#pragma unroll
  for (int c = 0; c < 7; ++c)
#pragma unroll
    for (int r = 0; r < 4; ++r) {
      int w = 16 * c + quad * 4 + r;
      if (w < WAY) dst[(size_t)w * DD + k0 + l15] = acc[c][r];
    }
}

// ---------------- mus update + musq (reduces 8 CP partials; k-split grid (100,4) — R1/R4-proven) -
__global__ __launch_bounds__(256) void k_musup(const float* __restrict__ musR, const float* __restrict__ SL,
                                               const float* __restrict__ CPp, float* __restrict__ musW,
                                               short* __restrict__ musb, float* __restrict__ musqP) {
  int w = blockIdx.x, tid = threadIdx.x;
  int kb = blockIdx.y * 1024;
  __shared__ float red[256];
  float q = 0.f;
  for (int k = kb + tid; k < kb + 1024; k += 256) {
    size_t o = (size_t)w * DD + k;
    float c = 0.f;
#pragma unroll
    for (int s = 0; s < 8; ++s) c += CPp[(size_t)s * CPS + o];
    float emus = (SL[o] + c) / 20.0f;   // p.sum(0) == 5 + 15 exactly
    float m = musR[o];
    float v = m + 0.2f * (emus - m);
    musW[o] = v;
    musb[o] = f2bs(v);
    q += v * v;
  }
  red[tid] = q; __syncthreads();
  for (int o = 128; o > 0; o >>= 1) { if (tid < o) red[tid] += red[tid + o]; __syncthreads(); }
  if (tid == 0) musqP[(size_t)w * 256 + blockIdx.y] = red[0];   // slots 4..255 stay zero (musinit)
}

__global__ void k_acc(const unsigned* __restrict__ ctr, float* __restrict__ out) {
  if (threadIdx.x == 0) out[N_U * WAY] = (float)(*ctr) / 1500.0f;
}

// ---------------- host ----------------
extern "C" void kernel_launch(void* const* d_in, const int* in_sizes, int n_in,
                              void* d_out, int out_size, void* d_ws, size_t ws_size,
                              hipStream_t stream) {
  const float* X = (const float*)d_in[0];
  const int* labels = (const int*)d_in[1];
  float* out = (float*)d_out;
  float* ws = (float*)d_ws;

  float* Z     = ws + OFF_Z;
  short* Zb    = (short*)(ws + OFF_Z);       // overlays Z rows 0..768 (sequenced via 2 launches)
  float* CPp   = ws + OFF_CPP;               // dead fp32 Z region after zb
  float* meanL = ws + OFF_MEANL;
  float* meanU = ws + OFF_MEANU;
  float* SL    = ws + OFF_SL;
  float* musA  = ws + OFF_MUSA;
  float* musB  = ws + OFF_MUSB;
  float* musqP = ws + OFF_MUSQP;
  short* musb16 = (short*)(ws + OFF_MUSB16);
  short* PTH   = (short*)(ws + OFF_PTH);
  short* PTL   = (short*)(ws + OFF_PTL);
  float* Kmat  = ws + OFF_KMAT;
  float* colsP = ws + OFF_COLS;
  float* misc_f = ws + OFF_MISC;
  unsigned* misc_u = (unsigned*)(ws + OFF_MISC);
  short* ZTH   = (short*)(ws + OFF_ZUT);
  short* ZTL   = (short*)(ws + OFF_ZUTL);
  float* aG    = ws + OFF_AG;
  float* prevG = ws + OFF_PREVG;
  float* binit = ws + OFF_BINIT;

  k_pow_norm<<<N_TOT, 256, 0, stream>>>(X, Z, meanL, misc_u, aG);
  k_colmeans<<<dim3(16, 25), 256, 0, stream>>>(Z, meanL, meanU);
  k_center<<<N_TOT, 256, 0, stream>>>(Z, meanL, meanU);
  k_musinit<<<WAY, 256, 0, stream>>>(Z, SL, musA, musb16, musqP, binit, PTH, PTL);
  k_zt<<<dim3(128, 48), 256, 0, stream>>>(Z, ZTH, ZTL);
  k_zb<<<1536, 256, 0, stream>>>(Z, Zb, 0);    // lo half: no src/dst overlap
  k_zb<<<1536, 256, 0, stream>>>(Z, Zb, 768);  // hi half: overlaps only consumed sources

  float* musR = musA;
  float* musW = musB;
  for (int e = 0; e < 20; ++e) {
    k_gemm1K<<<96, 256, 0, stream>>>(Zb, musb16, musqP, Kmat, misc_u);
    k_sink<<<SINK_BLOCKS, SINK_T, 0, stream>>>(Kmat, PTH, PTL, colsP, aG, prevG, binit, misc_u, misc_f,
                                               labels, out, 0);
    k_gemm2<<<dim3(256, 8), 64, 0, stream>>>(PTH, PTL, ZTH, ZTL, CPp);
    k_musup<<<dim3(WAY, 4), 256, 0, stream>>>(musR, SL, CPp, musW, musb16, musqP);
    float* tmp = musR; musR = musW; musW = tmp;
  }
  k_gemm1K<<<96, 256, 0, stream>>>(Zb, musb16, musqP, Kmat, misc_u);
  k_sink<<<SINK_BLOCKS, SINK_T, 0, stream>>>(Kmat, PTH, PTL, colsP, aG, prevG, binit, misc_u, misc_f,
                                             labels, out, 1);
  k_acc<<<1, 64, 0, stream>>>(misc_u + 5, out);
}